// Round 8
// baseline (867.014 us; speedup 1.0000x reference)
//
#include <hip/hip_runtime.h>

#define MM 2048     // memory slots
#define BB 64       // batch
#define TT 4        // tokens per slot
#define DD 128      // embed dim
#define VV 50000    // vocab
#define VPAD 50176  // VV rounded up to multiple of 256
#define NPART 392   // gemm partial slots / v-tiles of 128
#define NBLK 512    // grid size; co-resident by construction (see launch_bounds)
#define NBAR 16     // barrier slots (10 used)

typedef float f4v __attribute__((ext_vector_type(4)));
typedef short s8v __attribute__((ext_vector_type(8)));

// float -> bf16 bits (RNE)
__device__ __forceinline__ unsigned short f2bf(float f) {
    unsigned int u = __float_as_uint(f);
    u = u + 0x7FFFu + ((u >> 16) & 1u);
    return (unsigned short)(u >> 16);
}

// LDS overlay: phases are barrier-separated; 52224 B max -> 3 blocks/CU by LDS.
union LdsU {
    short gp[192 * 136];                                  // gemm_p: 128 C + 64 u rows
    struct { float Wl[64 * 68]; float Cl[64 * 136]; } go; // gemm_o
    float red[64];                                        // attn reduction
};

// ---- init: zero u + W (contiguous, 804864 float4) and barrier counters ----
__global__ void k_binit(float4* __restrict__ p, unsigned* __restrict__ bar) {
    const int i = blockIdx.x * 256 + threadIdx.x;
    p[i] = make_float4(0.f, 0.f, 0.f, 0.f);
    if (i < NBAR) bar[i] = 0u;
}

// ---- manual grid barrier: single-use counter per sync point ----
// All NBLK blocks are co-resident (launch_bounds(256,2) + 52.2KB LDS => cap 512).
// Bounded spin: if co-residency ever failed, we fail cleanly (no hang).
__device__ __forceinline__ void gbar(unsigned* __restrict__ bar, int idx) {
    __syncthreads();
    if (threadIdx.x == 0) {
        __threadfence();                 // release: publish this block's writes
        unsigned* c = bar + idx;
        atomicAdd(c, 1u);                // device-scope
        int polls = 0;
        while (__hip_atomic_load(c, __ATOMIC_RELAXED,
                                 __HIP_MEMORY_SCOPE_AGENT) < (unsigned)NBLK) {
            __builtin_amdgcn_s_sleep(2);
            if (++polls > (1 << 18)) break;   // ~65 ms bound: no deadlock
        }
        __threadfence();                 // acquire: see all published writes
    }
    __syncthreads();
}

// ---- phase: GEMM1, 128 v-rows per block (MFMA bf16) ----
// LDS rows 0..127 = C tile, 128..191 = u. Wave w: rows 32w..32w+31 as two
// 16-row groups; 4 k-steps x 4 b-tiles x 2 groups = 32 MFMA.
__device__ __forceinline__ void gemm_p128(LdsU& L, int tile, int t,
                                          const float* __restrict__ Ch,
                                          const float* __restrict__ u,
                                          float* __restrict__ P) {
    short* lds = L.gp;
    const int v0 = tile * 128;
#pragma unroll
    for (int i = 0; i < 24; ++i) {
        const int G = i * 256 + t;        // f4-index, 6144 total
        const int row = G >> 5;           // 0..191
        const int c4 = G & 31;
        float4 val;
        if (row < 128) {
            const int v = v0 + row;
            val = (v < VV) ? *(const float4*)(Ch + (size_t)v * DD + c4 * 4)
                           : make_float4(0.f, 0.f, 0.f, 0.f);
        } else {
            val = *(const float4*)(u + (size_t)(row - 128) * DD + c4 * 4);
        }
        const unsigned int lo = ((unsigned int)f2bf(val.y) << 16) | f2bf(val.x);
        const unsigned int hi = ((unsigned int)f2bf(val.w) << 16) | f2bf(val.z);
        *(uint2*)(lds + row * 136 + c4 * 4) = make_uint2(lo, hi);
    }
    __syncthreads();

    const int l = t & 63;
    const int w = t >> 6;
    const int quad = l >> 4;
    const int n16 = l & 15;

    const int ar0 = (32 * w + n16) * 136;
    const int ar1 = (32 * w + 16 + n16) * 136;
    const int br0 = (128 + n16) * 136;
    const int br1 = (144 + n16) * 136;
    const int br2 = (160 + n16) * 136;
    const int br3 = (176 + n16) * 136;

    f4v c00 = {0.f, 0.f, 0.f, 0.f}, c01 = c00, c02 = c00, c03 = c00;
    f4v c10 = c00, c11 = c00, c12 = c00, c13 = c00;

#pragma unroll
    for (int s = 0; s < 4; ++s) {
        const int ko = s * 32 + quad * 8;
        const s8v a0 = *(const s8v*)(lds + ar0 + ko);
        const s8v a1 = *(const s8v*)(lds + ar1 + ko);
        const s8v b0 = *(const s8v*)(lds + br0 + ko);
        const s8v b1 = *(const s8v*)(lds + br1 + ko);
        const s8v b2 = *(const s8v*)(lds + br2 + ko);
        const s8v b3 = *(const s8v*)(lds + br3 + ko);
        c00 = __builtin_amdgcn_mfma_f32_16x16x32_bf16(a0, b0, c00, 0, 0, 0);
        c01 = __builtin_amdgcn_mfma_f32_16x16x32_bf16(a0, b1, c01, 0, 0, 0);
        c02 = __builtin_amdgcn_mfma_f32_16x16x32_bf16(a0, b2, c02, 0, 0, 0);
        c03 = __builtin_amdgcn_mfma_f32_16x16x32_bf16(a0, b3, c03, 0, 0, 0);
        c10 = __builtin_amdgcn_mfma_f32_16x16x32_bf16(a1, b0, c10, 0, 0, 0);
        c11 = __builtin_amdgcn_mfma_f32_16x16x32_bf16(a1, b1, c11, 0, 0, 0);
        c12 = __builtin_amdgcn_mfma_f32_16x16x32_bf16(a1, b2, c12, 0, 0, 0);
        c13 = __builtin_amdgcn_mfma_f32_16x16x32_bf16(a1, b3, c13, 0, 0, 0);
    }

    const int vb0 = v0 + 32 * w + quad * 4;
    const int vb1 = vb0 + 16;
#pragma unroll
    for (int r = 0; r < 4; ++r) {
        float* __restrict__ P0 = P + (size_t)(vb0 + r) * 64 + n16;
        P0[0] = c00[r]; P0[16] = c01[r]; P0[32] = c02[r]; P0[48] = c03[r];
        float* __restrict__ P1 = P + (size_t)(vb1 + r) * 64 + n16;
        P1[0] = c10[r]; P1[16] = c11[r]; P1[32] = c12[r]; P1[48] = c13[r];
    }
}

// ---- phase: attention (block-local softmax, no max-sub), 1 block per b ----
__device__ __forceinline__ void attn256(LdsU& L, int b, int t,
                                        const int* __restrict__ st,
                                        const float* __restrict__ P,
                                        float* __restrict__ W) {
    int4 tk[8];
    float e[8];
#pragma unroll
    for (int k = 0; k < 8; ++k)
        tk[k] = *(const int4*)(st + ((size_t)(t + 256 * k) * 64 + b) * 4);
#pragma unroll
    for (int k = 0; k < 8; ++k) {
        float s = 0.f;
        if (tk[k].x) s += P[(size_t)tk[k].x * 64 + b];
        if (tk[k].y) s += P[(size_t)tk[k].y * 64 + b];
        if (tk[k].z) s += P[(size_t)tk[k].z * 64 + b];
        if (tk[k].w) s += P[(size_t)tk[k].w * 64 + b];
        e[k] = __expf(s);
    }
    float sum = ((e[0] + e[1]) + (e[2] + e[3])) + ((e[4] + e[5]) + (e[6] + e[7]));
#pragma unroll
    for (int off = 32; off; off >>= 1) sum += __shfl_xor(sum, off, 64);
    if ((t & 63) == 0) L.red[t >> 6] = sum;
    __syncthreads();
    const float inv = 1.f / ((L.red[0] + L.red[1]) + (L.red[2] + L.red[3]));
#pragma unroll
    for (int k = 0; k < 8; ++k) {
        const float p = e[k] * inv;
        if (tk[k].x) atomicAdd(W + (size_t)tk[k].x * 64 + b, p);
        if (tk[k].y) atomicAdd(W + (size_t)tk[k].y * 64 + b, p);
        if (tk[k].z) atomicAdd(W + (size_t)tk[k].z * 64 + b, p);
        if (tk[k].w) atomicAdd(W + (size_t)tk[k].w * 64 + b, p);
    }
    __syncthreads();
}

// ---- phase: GEMM2 fp32 tiled, one 128-v slice per block; W zero-writeback ----
__device__ __forceinline__ void gemm_o_tile(LdsU& L, int tile, int t,
                                            const float* __restrict__ C2,
                                            float* __restrict__ W,
                                            float* __restrict__ upart,
                                            const int rezero) {
    float* Wl = L.go.Wl;
    float* Cl = L.go.Cl;
    const int g = t >> 7;
    const int b0 = ((t >> 4) & 7) * 8;
    const int d0 = (t & 15) * 8;
    const int vb = tile * 128;

    f4v a0l = {0.f, 0.f, 0.f, 0.f}, a0h = a0l, a1l = a0l, a1h = a0l;
    f4v a2l = a0l, a2h = a0l, a3l = a0l, a3h = a0l;
    f4v a4l = a0l, a4h = a0l, a5l = a0l, a5h = a0l;
    f4v a6l = a0l, a6h = a0l, a7l = a0l, a7h = a0l;

    for (int cc = 0; cc < 2; ++cc) {
        const int vc = vb + cc * 64;
#pragma unroll
        for (int i = 0; i < 4; ++i) {
            const int G = i * 256 + t;
            const int row = G >> 4, c4 = G & 15;
            float* wp = W + (size_t)(vc + row) * 64 + c4 * 4;
            const float4 val = *(const float4*)wp;
            *(float4*)&Wl[row * 68 + c4 * 4] = val;
            if (rezero) *(float4*)wp = make_float4(0.f, 0.f, 0.f, 0.f);
        }
#pragma unroll
        for (int i = 0; i < 8; ++i) {
            const int G = i * 256 + t;
            const int row = G >> 5, c4 = G & 31;
            const int v = vc + row;
            float4 val = (v < VV) ? *(const float4*)(C2 + (size_t)v * DD + c4 * 4)
                                  : make_float4(0.f, 0.f, 0.f, 0.f);
            *(float4*)&Cl[row * 136 + c4 * 4] = val;
        }
        __syncthreads();

#define FMA_ROW(al, ah, wc)            \
    al += wc * cA; ah += wc * cB;
#pragma unroll
        for (int j = 0; j < 32; ++j) {
            const int kk = g * 32 + j;
            const f4v wA = *(const f4v*)&Wl[kk * 68 + b0];
            const f4v wB = *(const f4v*)&Wl[kk * 68 + b0 + 4];
            const f4v cA = *(const f4v*)&Cl[kk * 136 + d0];
            const f4v cB = *(const f4v*)&Cl[kk * 136 + d0 + 4];
            FMA_ROW(a0l, a0h, wA[0]) FMA_ROW(a1l, a1h, wA[1])
            FMA_ROW(a2l, a2h, wA[2]) FMA_ROW(a3l, a3h, wA[3])
            FMA_ROW(a4l, a4h, wB[0]) FMA_ROW(a5l, a5h, wB[1])
            FMA_ROW(a6l, a6h, wB[2]) FMA_ROW(a7l, a7h, wB[3])
        }
#undef FMA_ROW
        __syncthreads();
    }

    if (g == 1) {
#define STL(i, al, ah)                                   \
        *(f4v*)&Cl[(b0 + i) * 136 + d0] = al;            \
        *(f4v*)&Cl[(b0 + i) * 136 + d0 + 4] = ah;
        STL(0, a0l, a0h) STL(1, a1l, a1h) STL(2, a2l, a2h) STL(3, a3l, a3h)
        STL(4, a4l, a4h) STL(5, a5l, a5h) STL(6, a6l, a6h) STL(7, a7l, a7h)
#undef STL
    }
    __syncthreads();
    if (g == 0) {
        float* __restrict__ up = upart + (size_t)tile * (BB * DD);
#define STG(i, al, ah) {                                             \
        const f4v xl = al + *(const f4v*)&Cl[(b0 + i) * 136 + d0];   \
        const f4v xh = ah + *(const f4v*)&Cl[(b0 + i) * 136 + d0 + 4]; \
        *(f4v*)(up + (b0 + i) * DD + d0) = xl;                       \
        *(f4v*)(up + (b0 + i) * DD + d0 + 4) = xh; }
        STG(0, a0l, a0h) STG(1, a1l, a1h) STG(2, a2l, a2h) STG(3, a3l, a3h)
        STG(4, a4l, a4h) STG(5, a5l, a5h) STG(6, a6l, a6h) STG(7, a7l, a7h)
#undef STG
    }
    __syncthreads();
}

// ---- phase: reduce partials, dst[j] = u[j] + sum_k up[k][j] ----
__device__ __forceinline__ void reduce_unit(int unit, int t,
                                            const float* __restrict__ up,
                                            const float* __restrict__ u,
                                            float* __restrict__ dst) {
    const int j = unit * 256 + t;
    const float* __restrict__ p = up + j;
    float s = 0.f;
#pragma unroll 8
    for (int k = 0; k < NPART; ++k) s += p[(size_t)k * (BB * DD)];
    dst[j] = u[j] + s;
}

// ===================== the 1-dispatch pipeline =========================
__global__ __launch_bounds__(256, 2) void k_mega(const int* __restrict__ st,
                                                 const float* __restrict__ C,
                                                 float* __restrict__ u,
                                                 float* __restrict__ W,
                                                 float* __restrict__ P,
                                                 float* __restrict__ up,
                                                 unsigned* __restrict__ bar,
                                                 float* __restrict__ out) {
    __shared__ LdsU L;
    const int bid = blockIdx.x;
    const int t = threadIdx.x;

    // ---- hop 0: prob exactly uniform 1/2048 (u=0) -> scatter constant ----
    {
        const int g = bid * 256 + t;  // 512*256 == MM*BB exactly
        const int b = g & 63;
        const float p = 1.0f / (float)MM;
        const int4 tk = *(const int4*)(st + (size_t)g * 4);
        if (tk.x) atomicAdd(W + (size_t)tk.x * 64 + b, p);
        if (tk.y) atomicAdd(W + (size_t)tk.y * 64 + b, p);
        if (tk.z) atomicAdd(W + (size_t)tk.z * 64 + b, p);
        if (tk.w) atomicAdd(W + (size_t)tk.w * 64 + b, p);
    }
    gbar(bar, 0);
    if (bid < NPART) gemm_o_tile(L, bid, t, C + (size_t)1 * VV * DD, W, up, 1);
    gbar(bar, 1);
    if (bid < 32) reduce_unit(bid, t, up, u, u);
    gbar(bar, 2);

    // ---- hop 1 ----
    if (bid < NPART) gemm_p128(L, bid, t, C + (size_t)1 * VV * DD, u, P);
    gbar(bar, 3);
    if (bid < BB) attn256(L, bid, t, st, P, W);
    gbar(bar, 4);
    if (bid < NPART) gemm_o_tile(L, bid, t, C + (size_t)2 * VV * DD, W, up, 1);
    gbar(bar, 5);
    if (bid < 32) reduce_unit(bid, t, up, u, u);
    gbar(bar, 6);

    // ---- hop 2 ----
    if (bid < NPART) gemm_p128(L, bid, t, C + (size_t)2 * VV * DD, u, P);
    gbar(bar, 7);
    if (bid < BB) attn256(L, bid, t, st, P, W);
    gbar(bar, 8);
    if (bid < NPART) gemm_o_tile(L, bid, t, C + (size_t)3 * VV * DD, W, up, 0);
    gbar(bar, 9);
    if (bid < 32) reduce_unit(bid, t, up, u, out);
}

extern "C" void kernel_launch(void* const* d_in, const int* in_sizes, int n_in,
                              void* d_out, int out_size, void* d_ws, size_t ws_size,
                              hipStream_t stream) {
    const int* st = (const int*)d_in[0];
    const float* C = (const float*)d_in[1];

    float* u  = (float*)d_ws;                 // 8192 f, [b][d]
    float* W  = u + BB * DD;                  // VPAD*64 f (scatter target)
    float* P  = W + (size_t)VPAD * BB;        // VPAD*64 f (GEMM1 output)
    float* up = P + (size_t)VPAD * BB;        // NPART*8192 f partials
    unsigned* bar = (unsigned*)(up + (size_t)NPART * BB * DD);  // 16 counters

    // zero u + W (contiguous: (8192 + VPAD*64)/4 = 804864 float4) + barriers
    k_binit<<<(BB * DD + VPAD * BB) / 1024, 256, 0, stream>>>((float4*)u, bar);

    k_mega<<<NBLK, 256, 0, stream>>>(st, C, u, W, P, up, bar, (float*)d_out);
}

// Round 10
// 361.581 us; speedup vs baseline: 2.3978x; 2.3978x over previous
//
#include <hip/hip_runtime.h>

#define MM 2048     // memory slots
#define BB 64       // batch
#define TT 4        // tokens per slot
#define DD 128      // embed dim
#define VV 50000    // vocab
#define VPAD 50176  // VV rounded up to multiple of 256
#define NPART 392   // gemm_o partial slots (one per block)

typedef float f4v __attribute__((ext_vector_type(4)));
typedef short s8v __attribute__((ext_vector_type(8)));

// float -> bf16 bits (RNE)
__device__ __forceinline__ unsigned short f2bf(float f) {
    unsigned int u = __float_as_uint(f);
    u = u + 0x7FFFu + ((u >> 16) & 1u);
    return (unsigned short)(u >> 16);
}

// ---- init: zero u (8192 f) and W (VPAD*BB f) — contiguous in workspace ----
__global__ void k_init(float4* __restrict__ p) {
    p[blockIdx.x * 256 + threadIdx.x] = make_float4(0.f, 0.f, 0.f, 0.f);
}

// ---- hop 0 scatter: u=0 -> scores=0 -> prob EXACTLY 1/2048 (uniform). ----
__global__ __launch_bounds__(256) void k_scatter0(const int* __restrict__ st,
                                                  float* __restrict__ W) {
    const int g = blockIdx.x * 256 + threadIdx.x;  // g = m*64+b
    const int b = g & 63;
    const float p = 1.0f / (float)MM;              // exactly representable
    const int4 tk = *(const int4*)(st + (size_t)g * 4);
    if (tk.x) atomicAdd(W + (size_t)tk.x * 64 + b, p);
    if (tk.y) atomicAdd(W + (size_t)tk.y * 64 + b, p);
    if (tk.z) atomicAdd(W + (size_t)tk.z * 64 + b, p);
    if (tk.w) atomicAdd(W + (size_t)tk.w * 64 + b, p);
}

// ---- GEMM1 (MFMA bf16): P[v][b] = dot(C[h][v][:], u[b][:]) ----
__global__ __launch_bounds__(256, 4) void k_gemm_p(const float* __restrict__ Ch,
                                                   const float* __restrict__ u,
                                                   float* __restrict__ P) {
    __shared__ short lds[128 * 136];  // 34.8 KB bf16
    const int t = threadIdx.x;
    const int v0 = blockIdx.x * 64;

#pragma unroll
    for (int i = 0; i < 16; ++i) {
        const int G = i * 256 + t;        // f4-index
        const int row = G >> 5;           // 0..127
        const int c4 = G & 31;            // f4 within row
        float4 val;
        if (row < 64) {
            const int v = v0 + row;
            val = (v < VV) ? *(const float4*)(Ch + (size_t)v * DD + c4 * 4)
                           : make_float4(0.f, 0.f, 0.f, 0.f);
        } else {
            val = *(const float4*)(u + (size_t)(row - 64) * DD + c4 * 4);
        }
        const unsigned int lo = ((unsigned int)f2bf(val.y) << 16) | f2bf(val.x);
        const unsigned int hi = ((unsigned int)f2bf(val.w) << 16) | f2bf(val.z);
        *(uint2*)(lds + row * 136 + c4 * 4) = make_uint2(lo, hi);
    }
    __syncthreads();

    const int l = t & 63;
    const int w = t >> 6;       // wave id 0..3
    const int quad = l >> 4;    // 0..3
    const int n16 = l & 15;

    const int arow = (16 * w + n16) * 136;
    const int brow0 = (64 + 0 * 16 + n16) * 136;
    const int brow1 = (64 + 1 * 16 + n16) * 136;
    const int brow2 = (64 + 2 * 16 + n16) * 136;
    const int brow3 = (64 + 3 * 16 + n16) * 136;

    f4v ac0 = {0.f, 0.f, 0.f, 0.f}, ac1 = ac0, ac2 = ac0, ac3 = ac0;

#pragma unroll
    for (int s = 0; s < 4; ++s) {
        const int ko = s * 32 + quad * 8;
        const s8v av = *(const s8v*)(lds + arow + ko);
        const s8v b0 = *(const s8v*)(lds + brow0 + ko);
        const s8v b1 = *(const s8v*)(lds + brow1 + ko);
        const s8v b2 = *(const s8v*)(lds + brow2 + ko);
        const s8v b3 = *(const s8v*)(lds + brow3 + ko);
        ac0 = __builtin_amdgcn_mfma_f32_16x16x32_bf16(av, b0, ac0, 0, 0, 0);
        ac1 = __builtin_amdgcn_mfma_f32_16x16x32_bf16(av, b1, ac1, 0, 0, 0);
        ac2 = __builtin_amdgcn_mfma_f32_16x16x32_bf16(av, b2, ac2, 0, 0, 0);
        ac3 = __builtin_amdgcn_mfma_f32_16x16x32_bf16(av, b3, ac3, 0, 0, 0);
    }

    const int vbase = v0 + 16 * w + quad * 4;
#pragma unroll
    for (int r = 0; r < 4; ++r) {
        float* __restrict__ Pr = P + (size_t)(vbase + r) * 64 + n16;
        Pr[0]  = ac0[r];
        Pr[16] = ac1[r];
        Pr[32] = ac2[r];
        Pr[48] = ac3[r];
    }
}

// ---- fused attention: gather P -> softmax (no max-sub) -> scatter into W ----
__global__ __launch_bounds__(512) void k_attn(const int* __restrict__ st,
                                              const float* __restrict__ P,
                                              float* __restrict__ W) {
    const int b = blockIdx.x;
    const int tid = threadIdx.x;  // 0..511
    __shared__ float redsum[8];

    const int4 tk0 = *(const int4*)(st + ((size_t)(tid + 0)    * 64 + b) * 4);
    const int4 tk1 = *(const int4*)(st + ((size_t)(tid + 512)  * 64 + b) * 4);
    const int4 tk2 = *(const int4*)(st + ((size_t)(tid + 1024) * 64 + b) * 4);
    const int4 tk3 = *(const int4*)(st + ((size_t)(tid + 1536) * 64 + b) * 4);

    float v0 = 0.f, v1 = 0.f, v2 = 0.f, v3 = 0.f;
    if (tk0.x) v0 += P[(size_t)tk0.x * 64 + b];
    if (tk0.y) v0 += P[(size_t)tk0.y * 64 + b];
    if (tk0.z) v0 += P[(size_t)tk0.z * 64 + b];
    if (tk0.w) v0 += P[(size_t)tk0.w * 64 + b];
    if (tk1.x) v1 += P[(size_t)tk1.x * 64 + b];
    if (tk1.y) v1 += P[(size_t)tk1.y * 64 + b];
    if (tk1.z) v1 += P[(size_t)tk1.z * 64 + b];
    if (tk1.w) v1 += P[(size_t)tk1.w * 64 + b];
    if (tk2.x) v2 += P[(size_t)tk2.x * 64 + b];
    if (tk2.y) v2 += P[(size_t)tk2.y * 64 + b];
    if (tk2.z) v2 += P[(size_t)tk2.z * 64 + b];
    if (tk2.w) v2 += P[(size_t)tk2.w * 64 + b];
    if (tk3.x) v3 += P[(size_t)tk3.x * 64 + b];
    if (tk3.y) v3 += P[(size_t)tk3.y * 64 + b];
    if (tk3.z) v3 += P[(size_t)tk3.z * 64 + b];
    if (tk3.w) v3 += P[(size_t)tk3.w * 64 + b];

    v0 = __expf(v0); v1 = __expf(v1); v2 = __expf(v2); v3 = __expf(v3);
    float sum = (v0 + v1) + (v2 + v3);
#pragma unroll
    for (int off = 32; off; off >>= 1) sum += __shfl_xor(sum, off, 64);
    if ((tid & 63) == 0) redsum[tid >> 6] = sum;
    __syncthreads();
    float tot = redsum[0];
#pragma unroll
    for (int i = 1; i < 8; ++i) tot += redsum[i];
    const float inv = 1.f / tot;

    v0 *= inv; v1 *= inv; v2 *= inv; v3 *= inv;

    if (tk0.x) atomicAdd(W + (size_t)tk0.x * 64 + b, v0);
    if (tk0.y) atomicAdd(W + (size_t)tk0.y * 64 + b, v0);
    if (tk0.z) atomicAdd(W + (size_t)tk0.z * 64 + b, v0);
    if (tk0.w) atomicAdd(W + (size_t)tk0.w * 64 + b, v0);
    if (tk1.x) atomicAdd(W + (size_t)tk1.x * 64 + b, v1);
    if (tk1.y) atomicAdd(W + (size_t)tk1.y * 64 + b, v1);
    if (tk1.z) atomicAdd(W + (size_t)tk1.z * 64 + b, v1);
    if (tk1.w) atomicAdd(W + (size_t)tk1.w * 64 + b, v1);
    if (tk2.x) atomicAdd(W + (size_t)tk2.x * 64 + b, v2);
    if (tk2.y) atomicAdd(W + (size_t)tk2.y * 64 + b, v2);
    if (tk2.z) atomicAdd(W + (size_t)tk2.z * 64 + b, v2);
    if (tk2.w) atomicAdd(W + (size_t)tk2.w * 64 + b, v2);
    if (tk3.x) atomicAdd(W + (size_t)tk3.x * 64 + b, v3);
    if (tk3.y) atomicAdd(W + (size_t)tk3.y * 64 + b, v3);
    if (tk3.z) atomicAdd(W + (size_t)tk3.z * 64 + b, v3);
    if (tk3.w) atomicAdd(W + (size_t)tk3.w * 64 + b, v3);
}

// ---- GEMM2 (fp32 tiled): upart[block] = sum_v W[v][b] * C2[v][d] ----
__global__ __launch_bounds__(256, 3) void k_gemm_o(const float* __restrict__ C2,
                                                   float* __restrict__ W,
                                                   float* __restrict__ upart,
                                                   const int rezero) {
    __shared__ float Wl[64 * 68];    // 17.4 KB
    __shared__ float Cl[64 * 136];   // 34.8 KB (reused for k-group combine)
    const int t = threadIdx.x;
    const int g = t >> 7;            // k-group
    const int b0 = ((t >> 4) & 7) * 8;
    const int d0 = (t & 15) * 8;
    const int vb = blockIdx.x * 128;

    f4v a0l = {0.f, 0.f, 0.f, 0.f}, a0h = a0l, a1l = a0l, a1h = a0l;
    f4v a2l = a0l, a2h = a0l, a3l = a0l, a3h = a0l;
    f4v a4l = a0l, a4h = a0l, a5l = a0l, a5h = a0l;
    f4v a6l = a0l, a6h = a0l, a7l = a0l, a7h = a0l;

    for (int cc = 0; cc < 2; ++cc) {
        const int vc = vb + cc * 64;
#pragma unroll
        for (int i = 0; i < 4; ++i) {
            const int G = i * 256 + t;
            const int row = G >> 4, c4 = G & 15;
            float* wp = W + (size_t)(vc + row) * 64 + c4 * 4;
            const float4 val = *(const float4*)wp;
            *(float4*)&Wl[row * 68 + c4 * 4] = val;
            if (rezero) *(float4*)wp = make_float4(0.f, 0.f, 0.f, 0.f);
        }
#pragma unroll
        for (int i = 0; i < 8; ++i) {
            const int G = i * 256 + t;
            const int row = G >> 5, c4 = G & 31;
            const int v = vc + row;
            float4 val = (v < VV) ? *(const float4*)(C2 + (size_t)v * DD + c4 * 4)
                                  : make_float4(0.f, 0.f, 0.f, 0.f);
            *(float4*)&Cl[row * 136 + c4 * 4] = val;
        }
        __syncthreads();

#define FMA_ROW(al, ah, wc)            \
    al += wc * cA; ah += wc * cB;

#pragma unroll
        for (int j = 0; j < 32; ++j) {
            const int kk = g * 32 + j;
            const f4v wA = *(const f4v*)&Wl[kk * 68 + b0];
            const f4v wB = *(const f4v*)&Wl[kk * 68 + b0 + 4];
            const f4v cA = *(const f4v*)&Cl[kk * 136 + d0];
            const f4v cB = *(const f4v*)&Cl[kk * 136 + d0 + 4];
            FMA_ROW(a0l, a0h, wA[0]) FMA_ROW(a1l, a1h, wA[1])
            FMA_ROW(a2l, a2h, wA[2]) FMA_ROW(a3l, a3h, wA[3])
            FMA_ROW(a4l, a4h, wB[0]) FMA_ROW(a5l, a5h, wB[1])
            FMA_ROW(a6l, a6h, wB[2]) FMA_ROW(a7l, a7h, wB[3])
        }
#undef FMA_ROW
        __syncthreads();
    }

    if (g == 1) {
#define STL(i, al, ah)                                   \
        *(f4v*)&Cl[(b0 + i) * 136 + d0] = al;            \
        *(f4v*)&Cl[(b0 + i) * 136 + d0 + 4] = ah;
        STL(0, a0l, a0h) STL(1, a1l, a1h) STL(2, a2l, a2h) STL(3, a3l, a3h)
        STL(4, a4l, a4h) STL(5, a5l, a5h) STL(6, a6l, a6h) STL(7, a7l, a7h)
#undef STL
    }
    __syncthreads();
    if (g == 0) {
        float* __restrict__ up = upart + (size_t)blockIdx.x * (BB * DD);
#define STG(i, al, ah) {                                             \
        const f4v xl = al + *(const f4v*)&Cl[(b0 + i) * 136 + d0];   \
        const f4v xh = ah + *(const f4v*)&Cl[(b0 + i) * 136 + d0 + 4]; \
        *(f4v*)(up + (b0 + i) * DD + d0) = xl;                       \
        *(f4v*)(up + (b0 + i) * DD + d0 + 4) = xh; }
        STG(0, a0l, a0h) STG(1, a1l, a1h) STG(2, a2l, a2h) STG(3, a3l, a3h)
        STG(4, a4l, a4h) STG(5, a5l, a5h) STG(6, a6l, a6h) STG(7, a7l, a7h)
#undef STG
    }
}

// ---- reduce (hops 0,1): u[j] += partial sums; 256 blocks (32 jc x 8 kc),
// each block sums 49 partials then one atomicAdd per j — R2's proven-fast form.
__global__ __launch_bounds__(256) void k_reduce_a(const float* __restrict__ up,
                                                  float* __restrict__ u) {
    const int jc = blockIdx.x & 31;   // 32 j-chunks of 256
    const int kc = blockIdx.x >> 5;   // 8 k-chunks of 49
    const int j = jc * 256 + threadIdx.x;
    const float* __restrict__ p = up + (size_t)kc * 49 * (BB * DD) + j;
    float s = 0.f;
#pragma unroll 7
    for (int k = 0; k < 49; ++k) s += p[(size_t)k * (BB * DD)];
    atomicAdd(u + j, s);
}

// ---- final reduce (hop 2): out[j] = u[j] + sum over all 392 partials ----
// Owner-computes (out cannot be atomically accumulated without relying on
// external zeroing). 32 blocks, one j per thread.
__global__ __launch_bounds__(256) void k_reduce_fin(const float* __restrict__ up,
                                                    const float* __restrict__ u,
                                                    float* __restrict__ out) {
    const int j = blockIdx.x * 256 + threadIdx.x;  // 0..8191
    const float* __restrict__ p = up + j;
    float s = 0.f;
#pragma unroll 8
    for (int k = 0; k < NPART; ++k) s += p[(size_t)k * (BB * DD)];
    out[j] = u[j] + s;
}

extern "C" void kernel_launch(void* const* d_in, const int* in_sizes, int n_in,
                              void* d_out, int out_size, void* d_ws, size_t ws_size,
                              hipStream_t stream) {
    const int* st = (const int*)d_in[0];
    const float* C = (const float*)d_in[1];

    float* u  = (float*)d_ws;                 // 8192 f, [b][d]
    float* W  = u + BB * DD;                  // VPAD*64 f (scatter target)
    float* P  = W + (size_t)VPAD * BB;        // VPAD*64 f (GEMM1 output)
    float* up = P + (size_t)VPAD * BB;        // NPART*8192 f partials

    // zero u + W once; W self-cleans each hop via gemm_o writeback
    k_init<<<(BB * DD + VPAD * BB) / 1024, 256, 0, stream>>>((float4*)u);

    // ---- hop 0: prob exactly uniform 1/2048 (u=0) — no GEMM1/attn ----
    k_scatter0<<<(MM * BB) / 256, 256, 0, stream>>>(st, W);
    k_gemm_o<<<VPAD / 128, 256, 0, stream>>>(C + (size_t)1 * VV * DD, W, up, 1);
    k_reduce_a<<<256, 256, 0, stream>>>(up, u);

    // ---- hop 1 ----
    k_gemm_p<<<VPAD / 64, 256, 0, stream>>>(C + (size_t)1 * VV * DD, u, P);
    k_attn<<<BB, 512, 0, stream>>>(st, P, W);
    k_gemm_o<<<VPAD / 128, 256, 0, stream>>>(C + (size_t)2 * VV * DD, W, up, 1);
    k_reduce_a<<<256, 256, 0, stream>>>(up, u);

    // ---- hop 2 ----
    k_gemm_p<<<VPAD / 64, 256, 0, stream>>>(C + (size_t)2 * VV * DD, u, P);
    k_attn<<<BB, 512, 0, stream>>>(st, P, W);
    k_gemm_o<<<VPAD / 128, 256, 0, stream>>>(C + (size_t)3 * VV * DD, W, up, 0);
    k_reduce_fin<<<32, 256, 0, stream>>>(up, u, (float*)d_out);
}

// Round 11
// 326.898 us; speedup vs baseline: 2.6522x; 1.1061x over previous
//
#include <hip/hip_runtime.h>

#define MM 2048     // memory slots
#define BB 64       // batch
#define TT 4        // tokens per slot
#define DD 128      // embed dim
#define VV 50000    // vocab
#define VPAD 50176  // VV rounded up to multiple of 256
#define NPART 392   // gemm_o partial slots (one per block)

typedef float f4v __attribute__((ext_vector_type(4)));
typedef short s8v __attribute__((ext_vector_type(8)));

// float -> bf16 bits (RNE)
__device__ __forceinline__ unsigned short f2bf(float f) {
    unsigned int u = __float_as_uint(f);
    u = u + 0x7FFFu + ((u >> 16) & 1u);
    return (unsigned short)(u >> 16);
}

// ---- init: zero u (8192 f) and W (VPAD*BB f) — contiguous in workspace ----
__global__ void k_init(float4* __restrict__ p) {
    p[blockIdx.x * 256 + threadIdx.x] = make_float4(0.f, 0.f, 0.f, 0.f);
}

// ---- hop 0 scatter: u=0 -> scores=0 -> prob EXACTLY 1/2048 (uniform). ----
__global__ __launch_bounds__(256) void k_scatter0(const int* __restrict__ st,
                                                  float* __restrict__ W) {
    const int g = blockIdx.x * 256 + threadIdx.x;  // g = m*64+b
    const int b = g & 63;
    const float p = 1.0f / (float)MM;              // exactly representable
    const int4 tk = *(const int4*)(st + (size_t)g * 4);
    if (tk.x) atomicAdd(W + (size_t)tk.x * 64 + b, p);
    if (tk.y) atomicAdd(W + (size_t)tk.y * 64 + b, p);
    if (tk.z) atomicAdd(W + (size_t)tk.z * 64 + b, p);
    if (tk.w) atomicAdd(W + (size_t)tk.w * 64 + b, p);
}

// ---- GEMM1 (MFMA bf16): P[v][b] = dot(C[h][v][:], u[b][:]) ----
// 128 v-rows per block (R8-verified body). LDS rows 0..127 = C tile,
// 128..191 = u. Wave w: rows 32w..32w+31 as two 16-row groups.
__global__ __launch_bounds__(256, 3) void k_gemm_p(const float* __restrict__ Ch,
                                                   const float* __restrict__ u,
                                                   float* __restrict__ P) {
    __shared__ short lds[192 * 136];  // 52.2 KB bf16 -> 3 blocks/CU
    const int t = threadIdx.x;
    const int v0 = blockIdx.x * 128;

#pragma unroll
    for (int i = 0; i < 24; ++i) {
        const int G = i * 256 + t;        // f4-index, 6144 total
        const int row = G >> 5;           // 0..191
        const int c4 = G & 31;
        float4 val;
        if (row < 128) {
            const int v = v0 + row;
            val = (v < VV) ? *(const float4*)(Ch + (size_t)v * DD + c4 * 4)
                           : make_float4(0.f, 0.f, 0.f, 0.f);
        } else {
            val = *(const float4*)(u + (size_t)(row - 128) * DD + c4 * 4);
        }
        const unsigned int lo = ((unsigned int)f2bf(val.y) << 16) | f2bf(val.x);
        const unsigned int hi = ((unsigned int)f2bf(val.w) << 16) | f2bf(val.z);
        *(uint2*)(lds + row * 136 + c4 * 4) = make_uint2(lo, hi);
    }
    __syncthreads();

    const int l = t & 63;
    const int w = t >> 6;
    const int quad = l >> 4;
    const int n16 = l & 15;

    const int ar0 = (32 * w + n16) * 136;
    const int ar1 = (32 * w + 16 + n16) * 136;
    const int br0 = (128 + n16) * 136;
    const int br1 = (144 + n16) * 136;
    const int br2 = (160 + n16) * 136;
    const int br3 = (176 + n16) * 136;

    f4v c00 = {0.f, 0.f, 0.f, 0.f}, c01 = c00, c02 = c00, c03 = c00;
    f4v c10 = c00, c11 = c00, c12 = c00, c13 = c00;

#pragma unroll
    for (int s = 0; s < 4; ++s) {
        const int ko = s * 32 + quad * 8;
        const s8v a0 = *(const s8v*)(lds + ar0 + ko);
        const s8v a1 = *(const s8v*)(lds + ar1 + ko);
        const s8v b0 = *(const s8v*)(lds + br0 + ko);
        const s8v b1 = *(const s8v*)(lds + br1 + ko);
        const s8v b2 = *(const s8v*)(lds + br2 + ko);
        const s8v b3 = *(const s8v*)(lds + br3 + ko);
        c00 = __builtin_amdgcn_mfma_f32_16x16x32_bf16(a0, b0, c00, 0, 0, 0);
        c01 = __builtin_amdgcn_mfma_f32_16x16x32_bf16(a0, b1, c01, 0, 0, 0);
        c02 = __builtin_amdgcn_mfma_f32_16x16x32_bf16(a0, b2, c02, 0, 0, 0);
        c03 = __builtin_amdgcn_mfma_f32_16x16x32_bf16(a0, b3, c03, 0, 0, 0);
        c10 = __builtin_amdgcn_mfma_f32_16x16x32_bf16(a1, b0, c10, 0, 0, 0);
        c11 = __builtin_amdgcn_mfma_f32_16x16x32_bf16(a1, b1, c11, 0, 0, 0);
        c12 = __builtin_amdgcn_mfma_f32_16x16x32_bf16(a1, b2, c12, 0, 0, 0);
        c13 = __builtin_amdgcn_mfma_f32_16x16x32_bf16(a1, b3, c13, 0, 0, 0);
    }

    const int vb0 = v0 + 32 * w + quad * 4;
    const int vb1 = vb0 + 16;
#pragma unroll
    for (int r = 0; r < 4; ++r) {
        float* __restrict__ P0 = P + (size_t)(vb0 + r) * 64 + n16;
        P0[0] = c00[r]; P0[16] = c01[r]; P0[32] = c02[r]; P0[48] = c03[r];
        float* __restrict__ P1 = P + (size_t)(vb1 + r) * 64 + n16;
        P1[0] = c10[r]; P1[16] = c11[r]; P1[32] = c12[r]; P1[48] = c13[r];
    }
}

// ---- fused attention: gather P -> softmax (no max-sub) -> scatter into W ----
__global__ __launch_bounds__(512) void k_attn(const int* __restrict__ st,
                                              const float* __restrict__ P,
                                              float* __restrict__ W) {
    const int b = blockIdx.x;
    const int tid = threadIdx.x;  // 0..511
    __shared__ float redsum[8];

    const int4 tk0 = *(const int4*)(st + ((size_t)(tid + 0)    * 64 + b) * 4);
    const int4 tk1 = *(const int4*)(st + ((size_t)(tid + 512)  * 64 + b) * 4);
    const int4 tk2 = *(const int4*)(st + ((size_t)(tid + 1024) * 64 + b) * 4);
    const int4 tk3 = *(const int4*)(st + ((size_t)(tid + 1536) * 64 + b) * 4);

    float v0 = 0.f, v1 = 0.f, v2 = 0.f, v3 = 0.f;
    if (tk0.x) v0 += P[(size_t)tk0.x * 64 + b];
    if (tk0.y) v0 += P[(size_t)tk0.y * 64 + b];
    if (tk0.z) v0 += P[(size_t)tk0.z * 64 + b];
    if (tk0.w) v0 += P[(size_t)tk0.w * 64 + b];
    if (tk1.x) v1 += P[(size_t)tk1.x * 64 + b];
    if (tk1.y) v1 += P[(size_t)tk1.y * 64 + b];
    if (tk1.z) v1 += P[(size_t)tk1.z * 64 + b];
    if (tk1.w) v1 += P[(size_t)tk1.w * 64 + b];
    if (tk2.x) v2 += P[(size_t)tk2.x * 64 + b];
    if (tk2.y) v2 += P[(size_t)tk2.y * 64 + b];
    if (tk2.z) v2 += P[(size_t)tk2.z * 64 + b];
    if (tk2.w) v2 += P[(size_t)tk2.w * 64 + b];
    if (tk3.x) v3 += P[(size_t)tk3.x * 64 + b];
    if (tk3.y) v3 += P[(size_t)tk3.y * 64 + b];
    if (tk3.z) v3 += P[(size_t)tk3.z * 64 + b];
    if (tk3.w) v3 += P[(size_t)tk3.w * 64 + b];

    v0 = __expf(v0); v1 = __expf(v1); v2 = __expf(v2); v3 = __expf(v3);
    float sum = (v0 + v1) + (v2 + v3);
#pragma unroll
    for (int off = 32; off; off >>= 1) sum += __shfl_xor(sum, off, 64);
    if ((tid & 63) == 0) redsum[tid >> 6] = sum;
    __syncthreads();
    float tot = redsum[0];
#pragma unroll
    for (int i = 1; i < 8; ++i) tot += redsum[i];
    const float inv = 1.f / tot;

    v0 *= inv; v1 *= inv; v2 *= inv; v3 *= inv;

    if (tk0.x) atomicAdd(W + (size_t)tk0.x * 64 + b, v0);
    if (tk0.y) atomicAdd(W + (size_t)tk0.y * 64 + b, v0);
    if (tk0.z) atomicAdd(W + (size_t)tk0.z * 64 + b, v0);
    if (tk0.w) atomicAdd(W + (size_t)tk0.w * 64 + b, v0);
    if (tk1.x) atomicAdd(W + (size_t)tk1.x * 64 + b, v1);
    if (tk1.y) atomicAdd(W + (size_t)tk1.y * 64 + b, v1);
    if (tk1.z) atomicAdd(W + (size_t)tk1.z * 64 + b, v1);
    if (tk1.w) atomicAdd(W + (size_t)tk1.w * 64 + b, v1);
    if (tk2.x) atomicAdd(W + (size_t)tk2.x * 64 + b, v2);
    if (tk2.y) atomicAdd(W + (size_t)tk2.y * 64 + b, v2);
    if (tk2.z) atomicAdd(W + (size_t)tk2.z * 64 + b, v2);
    if (tk2.w) atomicAdd(W + (size_t)tk2.w * 64 + b, v2);
    if (tk3.x) atomicAdd(W + (size_t)tk3.x * 64 + b, v3);
    if (tk3.y) atomicAdd(W + (size_t)tk3.y * 64 + b, v3);
    if (tk3.z) atomicAdd(W + (size_t)tk3.z * 64 + b, v3);
    if (tk3.w) atomicAdd(W + (size_t)tk3.w * 64 + b, v3);
}

// ---- GEMM2 (MFMA bf16): up[b][d] = sum_v W[v][b] * C2[v][d], 128-v/block ----
// K-dim is v -> both operands staged TRANSPOSED as bf16 v-pairs (1 uint =
// v,v+1): Wt[b][v/2], Ct[d][v/2], stride 68 uints (16B-aligned b128 reads).
// Wave w owns d-cols [32w,32w+32): 4 b-tiles x 2 d-tiles x 4 k-chunks = 32 MFMA.
// W zero-writeback preserved (each W float4 read exactly once in staging).
__global__ __launch_bounds__(256, 3) void k_gemm_o(const float* __restrict__ C2,
                                                   float* __restrict__ W,
                                                   float* __restrict__ upart,
                                                   const int rezero) {
    __shared__ unsigned Wt[64 * 68];    // 17.4 KB [b][v-pair]
    __shared__ unsigned Ct[128 * 68];   // 34.8 KB [d][v-pair]
    const int t = threadIdx.x;
    const int vb = blockIdx.x * 128;

    // stage W: 128v x 64b -> Wt (two rows per item, coalesced 256B rows)
#pragma unroll
    for (int i = 0; i < 4; ++i) {
        const int item = i * 256 + t;
        const int q = item & 15;          // b-quad
        const int p = item >> 4;          // v-pair 0..63
        float* w0 = W + (size_t)(vb + 2 * p) * 64 + 4 * q;
        float* w1 = W + (size_t)(vb + 2 * p + 1) * 64 + 4 * q;
        const float4 x = *(const float4*)w0;
        const float4 y = *(const float4*)w1;
        if (rezero) {
            *(float4*)w0 = make_float4(0.f, 0.f, 0.f, 0.f);
            *(float4*)w1 = make_float4(0.f, 0.f, 0.f, 0.f);
        }
        Wt[(4 * q + 0) * 68 + p] = ((unsigned)f2bf(y.x) << 16) | f2bf(x.x);
        Wt[(4 * q + 1) * 68 + p] = ((unsigned)f2bf(y.y) << 16) | f2bf(x.y);
        Wt[(4 * q + 2) * 68 + p] = ((unsigned)f2bf(y.z) << 16) | f2bf(x.z);
        Wt[(4 * q + 3) * 68 + p] = ((unsigned)f2bf(y.w) << 16) | f2bf(x.w);
    }
    // stage C2: 128v x 128d -> Ct (guard v < VV; coalesced 512B rows)
#pragma unroll
    for (int i = 0; i < 8; ++i) {
        const int item = i * 256 + t;
        const int q = item & 31;          // d-quad
        const int p = item >> 5;          // v-pair 0..63
        const int v0 = vb + 2 * p;
        const float4 x = (v0 < VV)
            ? *(const float4*)(C2 + (size_t)v0 * DD + 4 * q)
            : make_float4(0.f, 0.f, 0.f, 0.f);
        const float4 y = (v0 + 1 < VV)
            ? *(const float4*)(C2 + (size_t)(v0 + 1) * DD + 4 * q)
            : make_float4(0.f, 0.f, 0.f, 0.f);
        Ct[(4 * q + 0) * 68 + p] = ((unsigned)f2bf(y.x) << 16) | f2bf(x.x);
        Ct[(4 * q + 1) * 68 + p] = ((unsigned)f2bf(y.y) << 16) | f2bf(x.y);
        Ct[(4 * q + 2) * 68 + p] = ((unsigned)f2bf(y.z) << 16) | f2bf(x.z);
        Ct[(4 * q + 3) * 68 + p] = ((unsigned)f2bf(y.w) << 16) | f2bf(x.w);
    }
    __syncthreads();

    const int l = t & 63;
    const int w = t >> 6;       // wave: d-cols 32w..32w+31
    const int quad = l >> 4;    // k-group within fragment
    const int n16 = l & 15;

    f4v a00 = {0.f, 0.f, 0.f, 0.f}, a01 = a00;
    f4v a10 = a00, a11 = a00, a20 = a00, a21 = a00, a30 = a00, a31 = a00;

#pragma unroll
    for (int ch = 0; ch < 4; ++ch) {
        const int ku = ch * 16 + quad * 4;   // uint col: k = 2*ku..2*ku+7
        const s8v wa0 = *(const s8v*)&Wt[(0  + n16) * 68 + ku];
        const s8v wa1 = *(const s8v*)&Wt[(16 + n16) * 68 + ku];
        const s8v wa2 = *(const s8v*)&Wt[(32 + n16) * 68 + ku];
        const s8v wa3 = *(const s8v*)&Wt[(48 + n16) * 68 + ku];
        const s8v cb0 = *(const s8v*)&Ct[(w * 32 + n16) * 68 + ku];
        const s8v cb1 = *(const s8v*)&Ct[(w * 32 + 16 + n16) * 68 + ku];
        a00 = __builtin_amdgcn_mfma_f32_16x16x32_bf16(wa0, cb0, a00, 0, 0, 0);
        a01 = __builtin_amdgcn_mfma_f32_16x16x32_bf16(wa0, cb1, a01, 0, 0, 0);
        a10 = __builtin_amdgcn_mfma_f32_16x16x32_bf16(wa1, cb0, a10, 0, 0, 0);
        a11 = __builtin_amdgcn_mfma_f32_16x16x32_bf16(wa1, cb1, a11, 0, 0, 0);
        a20 = __builtin_amdgcn_mfma_f32_16x16x32_bf16(wa2, cb0, a20, 0, 0, 0);
        a21 = __builtin_amdgcn_mfma_f32_16x16x32_bf16(wa2, cb1, a21, 0, 0, 0);
        a30 = __builtin_amdgcn_mfma_f32_16x16x32_bf16(wa3, cb0, a30, 0, 0, 0);
        a31 = __builtin_amdgcn_mfma_f32_16x16x32_bf16(wa3, cb1, a31, 0, 0, 0);
    }

    // D layout: col(d) = n16, row(b) = quad*4 + r, per 16x16 tile
    float* __restrict__ up = upart + (size_t)blockIdx.x * (BB * DD);
    const int dc = w * 32 + n16;
#pragma unroll
    for (int r = 0; r < 4; ++r) {
        const int br = quad * 4 + r;
        up[(br +  0) * DD + dc]      = a00[r];
        up[(br +  0) * DD + dc + 16] = a01[r];
        up[(br + 16) * DD + dc]      = a10[r];
        up[(br + 16) * DD + dc + 16] = a11[r];
        up[(br + 32) * DD + dc]      = a20[r];
        up[(br + 32) * DD + dc + 16] = a21[r];
        up[(br + 48) * DD + dc]      = a30[r];
        up[(br + 48) * DD + dc + 16] = a31[r];
    }
}

// ---- reduce (hops 0,1): u[j] += partial sums; 256 blocks (32 jc x 8 kc) ----
__global__ __launch_bounds__(256) void k_reduce_a(const float* __restrict__ up,
                                                  float* __restrict__ u) {
    const int jc = blockIdx.x & 31;   // 32 j-chunks of 256
    const int kc = blockIdx.x >> 5;   // 8 k-chunks of 49
    const int j = jc * 256 + threadIdx.x;
    const float* __restrict__ p = up + (size_t)kc * 49 * (BB * DD) + j;
    float s = 0.f;
#pragma unroll 7
    for (int k = 0; k < 49; ++k) s += p[(size_t)k * (BB * DD)];
    atomicAdd(u + j, s);
}

// ---- final reduce (hop 2): out[j] = u[j] + sum over all 392 partials ----
__global__ __launch_bounds__(256) void k_reduce_fin(const float* __restrict__ up,
                                                    const float* __restrict__ u,
                                                    float* __restrict__ out) {
    const int j = blockIdx.x * 256 + threadIdx.x;  // 0..8191
    const float* __restrict__ p = up + j;
    float s = 0.f;
#pragma unroll 8
    for (int k = 0; k < NPART; ++k) s += p[(size_t)k * (BB * DD)];
    out[j] = u[j] + s;
}

extern "C" void kernel_launch(void* const* d_in, const int* in_sizes, int n_in,
                              void* d_out, int out_size, void* d_ws, size_t ws_size,
                              hipStream_t stream) {
    const int* st = (const int*)d_in[0];
    const float* C = (const float*)d_in[1];

    float* u  = (float*)d_ws;                 // 8192 f, [b][d]
    float* W  = u + BB * DD;                  // VPAD*64 f (scatter target)
    float* P  = W + (size_t)VPAD * BB;        // VPAD*64 f (GEMM1 output)
    float* up = P + (size_t)VPAD * BB;        // NPART*8192 f partials

    // zero u + W once; W self-cleans each hop via gemm_o writeback
    k_init<<<(BB * DD + VPAD * BB) / 1024, 256, 0, stream>>>((float4*)u);

    // ---- hop 0: prob exactly uniform 1/2048 (u=0) — no GEMM1/attn ----
    k_scatter0<<<(MM * BB) / 256, 256, 0, stream>>>(st, W);
    k_gemm_o<<<VPAD / 128, 256, 0, stream>>>(C + (size_t)1 * VV * DD, W, up, 1);
    k_reduce_a<<<256, 256, 0, stream>>>(up, u);

    // ---- hop 1 ----
    k_gemm_p<<<VPAD / 128, 256, 0, stream>>>(C + (size_t)1 * VV * DD, u, P);
    k_attn<<<BB, 512, 0, stream>>>(st, P, W);
    k_gemm_o<<<VPAD / 128, 256, 0, stream>>>(C + (size_t)2 * VV * DD, W, up, 1);
    k_reduce_a<<<256, 256, 0, stream>>>(up, u);

    // ---- hop 2 ----
    k_gemm_p<<<VPAD / 128, 256, 0, stream>>>(C + (size_t)2 * VV * DD, u, P);
    k_attn<<<BB, 512, 0, stream>>>(st, P, W);
    k_gemm_o<<<VPAD / 128, 256, 0, stream>>>(C + (size_t)3 * VV * DD, W, up, 0);
    k_reduce_fin<<<32, 256, 0, stream>>>(up, u, (float*)d_out);
}

// Round 12
// 315.168 us; speedup vs baseline: 2.7510x; 1.0372x over previous
//
#include <hip/hip_runtime.h>

#define MM 2048     // memory slots
#define BB 64       // batch
#define TT 4        // tokens per slot
#define DD 128      // embed dim
#define VV 50000    // vocab
#define VPAD 50176  // VV rounded up to multiple of 256
#define NPART 392   // gemm_o partial slots (one per block)
#define NATT 512    // attn blocks (Zp partial slots)

typedef float f4v __attribute__((ext_vector_type(4)));
typedef short s8v __attribute__((ext_vector_type(8)));

// float -> bf16 bits (RNE)
__device__ __forceinline__ unsigned short f2bf(float f) {
    unsigned int u = __float_as_uint(f);
    u = u + 0x7FFFu + ((u >> 16) & 1u);
    return (unsigned short)(u >> 16);
}

// ---- init: zero u (8192 f) and W (VPAD*BB f) — contiguous in workspace ----
__global__ void k_init(float4* __restrict__ p) {
    p[blockIdx.x * 256 + threadIdx.x] = make_float4(0.f, 0.f, 0.f, 0.f);
}

// ---- hop 0 scatter: u=0 -> scores=0 -> prob EXACTLY 1/2048 (uniform). ----
__global__ __launch_bounds__(256) void k_scatter0(const int* __restrict__ st,
                                                  float* __restrict__ W) {
    const int g = blockIdx.x * 256 + threadIdx.x;  // g = m*64+b
    const int b = g & 63;
    const float p = 1.0f / (float)MM;              // exactly representable
    const int4 tk = *(const int4*)(st + (size_t)g * 4);
    if (tk.x) atomicAdd(W + (size_t)tk.x * 64 + b, p);
    if (tk.y) atomicAdd(W + (size_t)tk.y * 64 + b, p);
    if (tk.z) atomicAdd(W + (size_t)tk.z * 64 + b, p);
    if (tk.w) atomicAdd(W + (size_t)tk.w * 64 + b, p);
}

// ---- GEMM1 (MFMA bf16): P[v][b] = dot(C[h][v][:], u[b][:]) ----
// 128 v-rows per block. LDS rows 0..127 = C tile, 128..191 = u.
__global__ __launch_bounds__(256, 3) void k_gemm_p(const float* __restrict__ Ch,
                                                   const float* __restrict__ u,
                                                   float* __restrict__ P) {
    __shared__ short lds[192 * 136];  // 52.2 KB bf16 -> 3 blocks/CU
    const int t = threadIdx.x;
    const int v0 = blockIdx.x * 128;

#pragma unroll
    for (int i = 0; i < 24; ++i) {
        const int G = i * 256 + t;        // f4-index, 6144 total
        const int row = G >> 5;           // 0..191
        const int c4 = G & 31;
        float4 val;
        if (row < 128) {
            const int v = v0 + row;
            val = (v < VV) ? *(const float4*)(Ch + (size_t)v * DD + c4 * 4)
                           : make_float4(0.f, 0.f, 0.f, 0.f);
        } else {
            val = *(const float4*)(u + (size_t)(row - 128) * DD + c4 * 4);
        }
        const unsigned int lo = ((unsigned int)f2bf(val.y) << 16) | f2bf(val.x);
        const unsigned int hi = ((unsigned int)f2bf(val.w) << 16) | f2bf(val.z);
        *(uint2*)(lds + row * 136 + c4 * 4) = make_uint2(lo, hi);
    }
    __syncthreads();

    const int l = t & 63;
    const int w = t >> 6;
    const int quad = l >> 4;
    const int n16 = l & 15;

    const int ar0 = (32 * w + n16) * 136;
    const int ar1 = (32 * w + 16 + n16) * 136;
    const int br0 = (128 + n16) * 136;
    const int br1 = (144 + n16) * 136;
    const int br2 = (160 + n16) * 136;
    const int br3 = (176 + n16) * 136;

    f4v c00 = {0.f, 0.f, 0.f, 0.f}, c01 = c00, c02 = c00, c03 = c00;
    f4v c10 = c00, c11 = c00, c12 = c00, c13 = c00;

#pragma unroll
    for (int s = 0; s < 4; ++s) {
        const int ko = s * 32 + quad * 8;
        const s8v a0 = *(const s8v*)(lds + ar0 + ko);
        const s8v a1 = *(const s8v*)(lds + ar1 + ko);
        const s8v b0 = *(const s8v*)(lds + br0 + ko);
        const s8v b1 = *(const s8v*)(lds + br1 + ko);
        const s8v b2 = *(const s8v*)(lds + br2 + ko);
        const s8v b3 = *(const s8v*)(lds + br3 + ko);
        c00 = __builtin_amdgcn_mfma_f32_16x16x32_bf16(a0, b0, c00, 0, 0, 0);
        c01 = __builtin_amdgcn_mfma_f32_16x16x32_bf16(a0, b1, c01, 0, 0, 0);
        c02 = __builtin_amdgcn_mfma_f32_16x16x32_bf16(a0, b2, c02, 0, 0, 0);
        c03 = __builtin_amdgcn_mfma_f32_16x16x32_bf16(a0, b3, c03, 0, 0, 0);
        c10 = __builtin_amdgcn_mfma_f32_16x16x32_bf16(a1, b0, c10, 0, 0, 0);
        c11 = __builtin_amdgcn_mfma_f32_16x16x32_bf16(a1, b1, c11, 0, 0, 0);
        c12 = __builtin_amdgcn_mfma_f32_16x16x32_bf16(a1, b2, c12, 0, 0, 0);
        c13 = __builtin_amdgcn_mfma_f32_16x16x32_bf16(a1, b3, c13, 0, 0, 0);
    }

    const int vb0 = v0 + 32 * w + quad * 4;
    const int vb1 = vb0 + 16;
#pragma unroll
    for (int r = 0; r < 4; ++r) {
        float* __restrict__ P0 = P + (size_t)(vb0 + r) * 64 + n16;
        P0[0] = c00[r]; P0[16] = c01[r]; P0[32] = c02[r]; P0[48] = c03[r];
        float* __restrict__ P1 = P + (size_t)(vb1 + r) * 64 + n16;
        P1[0] = c10[r]; P1[16] = c11[r]; P1[32] = c12[r]; P1[48] = c13[r];
    }
}

// ---- attention, m-parallel: scatter UNNORMALIZED e^s; Zp[bid][b] partials ----
// 512 blocks x 256 thr (8x CU coverage vs block-per-b). No max-sub (scores
// structurally tiny, R3-verified). Normalization 1/Z[b] applied in reduce.
__global__ __launch_bounds__(256) void k_attn2(const int* __restrict__ st,
                                               const float* __restrict__ P,
                                               float* __restrict__ W,
                                               float* __restrict__ Zp) {
    __shared__ float eb[256];
    const int tid = threadIdx.x;
    const int g = blockIdx.x * 256 + tid;  // g = m*64+b
    const int b = g & 63;

    const int4 tk = *(const int4*)(st + (size_t)g * 4);  // coalesced
    float s = 0.f;
    if (tk.x) s += P[(size_t)tk.x * 64 + b];
    if (tk.y) s += P[(size_t)tk.y * 64 + b];
    if (tk.z) s += P[(size_t)tk.z * 64 + b];
    if (tk.w) s += P[(size_t)tk.w * 64 + b];
    const float e = __expf(s);
    eb[tid] = e;

    if (tk.x) atomicAdd(W + (size_t)tk.x * 64 + b, e);
    if (tk.y) atomicAdd(W + (size_t)tk.y * 64 + b, e);
    if (tk.z) atomicAdd(W + (size_t)tk.z * 64 + b, e);
    if (tk.w) atomicAdd(W + (size_t)tk.w * 64 + b, e);

    __syncthreads();
    if (tid < 64)  // lane tid == b of the block's 4 m-rows; no atomics
        Zp[(size_t)blockIdx.x * 64 + tid] =
            (eb[tid] + eb[tid + 64]) + (eb[tid + 128] + eb[tid + 192]);
}

// ---- GEMM2 (MFMA bf16): up[b][d] = sum_v W[v][b] * C2[v][d], 128-v/block ----
__global__ __launch_bounds__(256, 3) void k_gemm_o(const float* __restrict__ C2,
                                                   float* __restrict__ W,
                                                   float* __restrict__ upart,
                                                   const int rezero) {
    __shared__ unsigned Wt[64 * 68];    // 17.4 KB [b][v-pair]
    __shared__ unsigned Ct[128 * 68];   // 34.8 KB [d][v-pair]
    const int t = threadIdx.x;
    const int vb = blockIdx.x * 128;

#pragma unroll
    for (int i = 0; i < 4; ++i) {
        const int item = i * 256 + t;
        const int q = item & 15;          // b-quad
        const int p = item >> 4;          // v-pair 0..63
        float* w0 = W + (size_t)(vb + 2 * p) * 64 + 4 * q;
        float* w1 = W + (size_t)(vb + 2 * p + 1) * 64 + 4 * q;
        const float4 x = *(const float4*)w0;
        const float4 y = *(const float4*)w1;
        if (rezero) {
            *(float4*)w0 = make_float4(0.f, 0.f, 0.f, 0.f);
            *(float4*)w1 = make_float4(0.f, 0.f, 0.f, 0.f);
        }
        Wt[(4 * q + 0) * 68 + p] = ((unsigned)f2bf(y.x) << 16) | f2bf(x.x);
        Wt[(4 * q + 1) * 68 + p] = ((unsigned)f2bf(y.y) << 16) | f2bf(x.y);
        Wt[(4 * q + 2) * 68 + p] = ((unsigned)f2bf(y.z) << 16) | f2bf(x.z);
        Wt[(4 * q + 3) * 68 + p] = ((unsigned)f2bf(y.w) << 16) | f2bf(x.w);
    }
#pragma unroll
    for (int i = 0; i < 8; ++i) {
        const int item = i * 256 + t;
        const int q = item & 31;          // d-quad
        const int p = item >> 5;          // v-pair 0..63
        const int v0 = vb + 2 * p;
        const float4 x = (v0 < VV)
            ? *(const float4*)(C2 + (size_t)v0 * DD + 4 * q)
            : make_float4(0.f, 0.f, 0.f, 0.f);
        const float4 y = (v0 + 1 < VV)
            ? *(const float4*)(C2 + (size_t)(v0 + 1) * DD + 4 * q)
            : make_float4(0.f, 0.f, 0.f, 0.f);
        Ct[(4 * q + 0) * 68 + p] = ((unsigned)f2bf(y.x) << 16) | f2bf(x.x);
        Ct[(4 * q + 1) * 68 + p] = ((unsigned)f2bf(y.y) << 16) | f2bf(x.y);
        Ct[(4 * q + 2) * 68 + p] = ((unsigned)f2bf(y.z) << 16) | f2bf(x.z);
        Ct[(4 * q + 3) * 68 + p] = ((unsigned)f2bf(y.w) << 16) | f2bf(x.w);
    }
    __syncthreads();

    const int l = t & 63;
    const int w = t >> 6;       // wave: d-cols 32w..32w+31
    const int quad = l >> 4;
    const int n16 = l & 15;

    f4v a00 = {0.f, 0.f, 0.f, 0.f}, a01 = a00;
    f4v a10 = a00, a11 = a00, a20 = a00, a21 = a00, a30 = a00, a31 = a00;

#pragma unroll
    for (int ch = 0; ch < 4; ++ch) {
        const int ku = ch * 16 + quad * 4;   // uint col: k = 2*ku..2*ku+7
        const s8v wa0 = *(const s8v*)&Wt[(0  + n16) * 68 + ku];
        const s8v wa1 = *(const s8v*)&Wt[(16 + n16) * 68 + ku];
        const s8v wa2 = *(const s8v*)&Wt[(32 + n16) * 68 + ku];
        const s8v wa3 = *(const s8v*)&Wt[(48 + n16) * 68 + ku];
        const s8v cb0 = *(const s8v*)&Ct[(w * 32 + n16) * 68 + ku];
        const s8v cb1 = *(const s8v*)&Ct[(w * 32 + 16 + n16) * 68 + ku];
        a00 = __builtin_amdgcn_mfma_f32_16x16x32_bf16(wa0, cb0, a00, 0, 0, 0);
        a01 = __builtin_amdgcn_mfma_f32_16x16x32_bf16(wa0, cb1, a01, 0, 0, 0);
        a10 = __builtin_amdgcn_mfma_f32_16x16x32_bf16(wa1, cb0, a10, 0, 0, 0);
        a11 = __builtin_amdgcn_mfma_f32_16x16x32_bf16(wa1, cb1, a11, 0, 0, 0);
        a20 = __builtin_amdgcn_mfma_f32_16x16x32_bf16(wa2, cb0, a20, 0, 0, 0);
        a21 = __builtin_amdgcn_mfma_f32_16x16x32_bf16(wa2, cb1, a21, 0, 0, 0);
        a30 = __builtin_amdgcn_mfma_f32_16x16x32_bf16(wa3, cb0, a30, 0, 0, 0);
        a31 = __builtin_amdgcn_mfma_f32_16x16x32_bf16(wa3, cb1, a31, 0, 0, 0);
    }

    float* __restrict__ up = upart + (size_t)blockIdx.x * (BB * DD);
    const int dc = w * 32 + n16;
#pragma unroll
    for (int r = 0; r < 4; ++r) {
        const int br = quad * 4 + r;
        up[(br +  0) * DD + dc]      = a00[r];
        up[(br +  0) * DD + dc + 16] = a01[r];
        up[(br + 16) * DD + dc]      = a10[r];
        up[(br + 16) * DD + dc + 16] = a11[r];
        up[(br + 32) * DD + dc]      = a20[r];
        up[(br + 32) * DD + dc + 16] = a21[r];
        up[(br + 48) * DD + dc]      = a30[r];
        up[(br + 48) * DD + dc + 16] = a31[r];
    }
}

// ---- block-local Z: sum 512 Zp partials for the 2 b-values this block owns.
// tid's b = b_base + (tid>>7); 128 threads per b, 4 partials each, tree-reduce.
__device__ __forceinline__ float zfor(const float* __restrict__ Zp,
                                      float* __restrict__ zw,
                                      int b_base, int tid) {
    const int bloc = tid >> 7;           // 0 or 1
    const int b = b_base + bloc;
    const int i = tid & 127;
    float z = (Zp[(size_t)(i +   0) * 64 + b] + Zp[(size_t)(i + 128) * 64 + b])
            + (Zp[(size_t)(i + 256) * 64 + b] + Zp[(size_t)(i + 384) * 64 + b]);
#pragma unroll
    for (int off = 32; off; off >>= 1) z += __shfl_xor(z, off, 64);
    if ((tid & 63) == 0) zw[tid >> 6] = z;
    __syncthreads();
    return (bloc == 0) ? (zw[0] + zw[1]) : (zw[2] + zw[3]);
}

// ---- reduce hop 0 (prob already exact): u[j] += partial sums ----
__global__ __launch_bounds__(256) void k_reduce_a(const float* __restrict__ up,
                                                  float* __restrict__ u) {
    const int jc = blockIdx.x & 31;   // 32 j-chunks of 256
    const int kc = blockIdx.x >> 5;   // 8 k-chunks of 49
    const int j = jc * 256 + threadIdx.x;
    const float* __restrict__ p = up + (size_t)kc * 49 * (BB * DD) + j;
    float s = 0.f;
#pragma unroll 7
    for (int k = 0; k < 49; ++k) s += p[(size_t)k * (BB * DD)];
    atomicAdd(u + j, s);
}

// ---- reduce hop 1 (unnormalized W): u[j] += s * (1/Z[b]) ----
__global__ __launch_bounds__(256) void k_reduce_az(const float* __restrict__ up,
                                                   const float* __restrict__ Zp,
                                                   float* __restrict__ u) {
    __shared__ float zw[4];
    const int jc = blockIdx.x & 31;
    const int kc = blockIdx.x >> 5;
    const int tid = threadIdx.x;
    const float Z = zfor(Zp, zw, jc * 2, tid);   // j>>7 = jc*2 + (tid>>7)
    const float rz = 1.f / Z;
    const int j = jc * 256 + tid;
    const float* __restrict__ p = up + (size_t)kc * 49 * (BB * DD) + j;
    float s = 0.f;
#pragma unroll 7
    for (int k = 0; k < 49; ++k) s += p[(size_t)k * (BB * DD)];
    atomicAdd(u + j, s * rz);
}

// ---- final reduce hop 2: out[j] = u[j] + (sum of 392 partials) * (1/Z[b]) ----
__global__ __launch_bounds__(256) void k_reduce_finz(const float* __restrict__ up,
                                                     const float* __restrict__ Zp,
                                                     const float* __restrict__ u,
                                                     float* __restrict__ out) {
    __shared__ float zw[4];
    const int tid = threadIdx.x;
    const float Z = zfor(Zp, zw, blockIdx.x * 2, tid);
    const float rz = 1.f / Z;
    const int j = blockIdx.x * 256 + tid;  // 0..8191
    const float* __restrict__ p = up + j;
    float s = 0.f;
#pragma unroll 8
    for (int k = 0; k < NPART; ++k) s += p[(size_t)k * (BB * DD)];
    out[j] = u[j] + s * rz;
}

extern "C" void kernel_launch(void* const* d_in, const int* in_sizes, int n_in,
                              void* d_out, int out_size, void* d_ws, size_t ws_size,
                              hipStream_t stream) {
    const int* st = (const int*)d_in[0];
    const float* C = (const float*)d_in[1];

    float* u  = (float*)d_ws;                 // 8192 f, [b][d]
    float* W  = u + BB * DD;                  // VPAD*64 f (scatter target)
    float* P  = W + (size_t)VPAD * BB;        // VPAD*64 f (GEMM1 output)
    float* up = P + (size_t)VPAD * BB;        // NPART*8192 f partials
    float* Zp = up + (size_t)NPART * BB * DD; // 512*64 f Z partials

    // zero u + W once; W self-cleans each hop via gemm_o writeback
    k_init<<<(BB * DD + VPAD * BB) / 1024, 256, 0, stream>>>((float4*)u);

    // ---- hop 0: prob exactly uniform 1/2048 (u=0) — no GEMM1/attn ----
    k_scatter0<<<(MM * BB) / 256, 256, 0, stream>>>(st, W);
    k_gemm_o<<<VPAD / 128, 256, 0, stream>>>(C + (size_t)1 * VV * DD, W, up, 1);
    k_reduce_a<<<256, 256, 0, stream>>>(up, u);

    // ---- hop 1 ----
    k_gemm_p<<<VPAD / 128, 256, 0, stream>>>(C + (size_t)1 * VV * DD, u, P);
    k_attn2<<<NATT, 256, 0, stream>>>(st, P, W, Zp);
    k_gemm_o<<<VPAD / 128, 256, 0, stream>>>(C + (size_t)2 * VV * DD, W, up, 1);
    k_reduce_az<<<256, 256, 0, stream>>>(up, Zp, u);

    // ---- hop 2 ----
    k_gemm_p<<<VPAD / 128, 256, 0, stream>>>(C + (size_t)2 * VV * DD, u, P);
    k_attn2<<<NATT, 256, 0, stream>>>(st, P, W, Zp);
    k_gemm_o<<<VPAD / 128, 256, 0, stream>>>(C + (size_t)3 * VV * DD, W, up, 0);
    k_reduce_finz<<<32, 256, 0, stream>>>(up, Zp, u, (float*)d_out);
}

// Round 13
// 312.336 us; speedup vs baseline: 2.7759x; 1.0091x over previous
//
#include <hip/hip_runtime.h>

#define MM 2048     // memory slots
#define BB 64       // batch
#define TT 4        // tokens per slot
#define DD 128      // embed dim
#define VV 50000    // vocab
#define VPAD 50176  // VV rounded up to multiple of 256
#define NPART 392   // gemm_o partial slots (one per block)
#define NATT 512    // attn blocks (Zp partial slots)

typedef float f4v __attribute__((ext_vector_type(4)));
typedef short s8v __attribute__((ext_vector_type(8)));

// float -> bf16 bits (RNE)
__device__ __forceinline__ unsigned short f2bf(float f) {
    unsigned int u = __float_as_uint(f);
    u = u + 0x7FFFu + ((u >> 16) & 1u);
    return (unsigned short)(u >> 16);
}
// bf16 bits -> float
__device__ __forceinline__ float bf2f(unsigned short s) {
    return __uint_as_float((unsigned)s << 16);
}
// pack two floats as bf16 pair
__device__ __forceinline__ unsigned pk2(float lo, float hi) {
    return ((unsigned)f2bf(hi) << 16) | f2bf(lo);
}

// ---- init: zero u (8192 f) and W (VPAD*BB f) — contiguous in workspace ----
__global__ void k_init(float4* __restrict__ p) {
    p[blockIdx.x * 256 + threadIdx.x] = make_float4(0.f, 0.f, 0.f, 0.f);
}

// ---- hop 0 scatter: u=0 -> scores=0 -> prob EXACTLY 1/2048 (uniform). ----
__global__ __launch_bounds__(256) void k_scatter0(const int* __restrict__ st,
                                                  float* __restrict__ W) {
    const int g = blockIdx.x * 256 + threadIdx.x;  // g = m*64+b
    const int b = g & 63;
    const float p = 1.0f / (float)MM;              // exactly representable
    const int4 tk = *(const int4*)(st + (size_t)g * 4);
    if (tk.x) atomicAdd(W + (size_t)tk.x * 64 + b, p);
    if (tk.y) atomicAdd(W + (size_t)tk.y * 64 + b, p);
    if (tk.z) atomicAdd(W + (size_t)tk.z * 64 + b, p);
    if (tk.w) atomicAdd(W + (size_t)tk.w * 64 + b, p);
}

// ---- GEMM1 (MFMA bf16): P[v][b] = dot(C[h][v][:], u[b][:]) ----
// 128 v-rows per block. LDS rows 0..127 = C tile, 128..191 = u.
__global__ __launch_bounds__(256, 3) void k_gemm_p(const float* __restrict__ Ch,
                                                   const float* __restrict__ u,
                                                   float* __restrict__ P) {
    __shared__ short lds[192 * 136];  // 52.2 KB bf16 -> 3 blocks/CU
    const int t = threadIdx.x;
    const int v0 = blockIdx.x * 128;

#pragma unroll
    for (int i = 0; i < 24; ++i) {
        const int G = i * 256 + t;        // f4-index, 6144 total
        const int row = G >> 5;           // 0..191
        const int c4 = G & 31;
        float4 val;
        if (row < 128) {
            const int v = v0 + row;
            val = (v < VV) ? *(const float4*)(Ch + (size_t)v * DD + c4 * 4)
                           : make_float4(0.f, 0.f, 0.f, 0.f);
        } else {
            val = *(const float4*)(u + (size_t)(row - 128) * DD + c4 * 4);
        }
        const unsigned int lo = ((unsigned int)f2bf(val.y) << 16) | f2bf(val.x);
        const unsigned int hi = ((unsigned int)f2bf(val.w) << 16) | f2bf(val.z);
        *(uint2*)(lds + row * 136 + c4 * 4) = make_uint2(lo, hi);
    }
    __syncthreads();

    const int l = t & 63;
    const int w = t >> 6;
    const int quad = l >> 4;
    const int n16 = l & 15;

    const int ar0 = (32 * w + n16) * 136;
    const int ar1 = (32 * w + 16 + n16) * 136;
    const int br0 = (128 + n16) * 136;
    const int br1 = (144 + n16) * 136;
    const int br2 = (160 + n16) * 136;
    const int br3 = (176 + n16) * 136;

    f4v c00 = {0.f, 0.f, 0.f, 0.f}, c01 = c00, c02 = c00, c03 = c00;
    f4v c10 = c00, c11 = c00, c12 = c00, c13 = c00;

#pragma unroll
    for (int s = 0; s < 4; ++s) {
        const int ko = s * 32 + quad * 8;
        const s8v a0 = *(const s8v*)(lds + ar0 + ko);
        const s8v a1 = *(const s8v*)(lds + ar1 + ko);
        const s8v b0 = *(const s8v*)(lds + br0 + ko);
        const s8v b1 = *(const s8v*)(lds + br1 + ko);
        const s8v b2 = *(const s8v*)(lds + br2 + ko);
        const s8v b3 = *(const s8v*)(lds + br3 + ko);
        c00 = __builtin_amdgcn_mfma_f32_16x16x32_bf16(a0, b0, c00, 0, 0, 0);
        c01 = __builtin_amdgcn_mfma_f32_16x16x32_bf16(a0, b1, c01, 0, 0, 0);
        c02 = __builtin_amdgcn_mfma_f32_16x16x32_bf16(a0, b2, c02, 0, 0, 0);
        c03 = __builtin_amdgcn_mfma_f32_16x16x32_bf16(a0, b3, c03, 0, 0, 0);
        c10 = __builtin_amdgcn_mfma_f32_16x16x32_bf16(a1, b0, c10, 0, 0, 0);
        c11 = __builtin_amdgcn_mfma_f32_16x16x32_bf16(a1, b1, c11, 0, 0, 0);
        c12 = __builtin_amdgcn_mfma_f32_16x16x32_bf16(a1, b2, c12, 0, 0, 0);
        c13 = __builtin_amdgcn_mfma_f32_16x16x32_bf16(a1, b3, c13, 0, 0, 0);
    }

    const int vb0 = v0 + 32 * w + quad * 4;
    const int vb1 = vb0 + 16;
#pragma unroll
    for (int r = 0; r < 4; ++r) {
        float* __restrict__ P0 = P + (size_t)(vb0 + r) * 64 + n16;
        P0[0] = c00[r]; P0[16] = c01[r]; P0[32] = c02[r]; P0[48] = c03[r];
        float* __restrict__ P1 = P + (size_t)(vb1 + r) * 64 + n16;
        P1[0] = c10[r]; P1[16] = c11[r]; P1[32] = c12[r]; P1[48] = c13[r];
    }
}

// ---- attention, m-parallel: scatter UNNORMALIZED e^s; Zp[bid][b] partials ----
__global__ __launch_bounds__(256) void k_attn2(const int* __restrict__ st,
                                               const float* __restrict__ P,
                                               float* __restrict__ W,
                                               float* __restrict__ Zp) {
    __shared__ float eb[256];
    const int tid = threadIdx.x;
    const int g = blockIdx.x * 256 + tid;  // g = m*64+b
    const int b = g & 63;

    const int4 tk = *(const int4*)(st + (size_t)g * 4);  // coalesced
    float s = 0.f;
    if (tk.x) s += P[(size_t)tk.x * 64 + b];
    if (tk.y) s += P[(size_t)tk.y * 64 + b];
    if (tk.z) s += P[(size_t)tk.z * 64 + b];
    if (tk.w) s += P[(size_t)tk.w * 64 + b];
    const float e = __expf(s);
    eb[tid] = e;

    if (tk.x) atomicAdd(W + (size_t)tk.x * 64 + b, e);
    if (tk.y) atomicAdd(W + (size_t)tk.y * 64 + b, e);
    if (tk.z) atomicAdd(W + (size_t)tk.z * 64 + b, e);
    if (tk.w) atomicAdd(W + (size_t)tk.w * 64 + b, e);

    __syncthreads();
    if (tid < 64)  // lane tid == b of the block's 4 m-rows; no atomics
        Zp[(size_t)blockIdx.x * 64 + tid] =
            (eb[tid] + eb[tid + 64]) + (eb[tid + 128] + eb[tid + 192]);
}

// ---- GEMM2 (MFMA bf16): partials PACKED bf16x2 -> upk[part][b][wi] ----
// word wi = w*16+n16 holds (d0, d0+16) where d0 = (wi>>4)*32 + (wi&15).
__global__ __launch_bounds__(256, 3) void k_gemm_o(const float* __restrict__ C2,
                                                   float* __restrict__ W,
                                                   unsigned* __restrict__ upk,
                                                   const int rezero) {
    __shared__ unsigned Wt[64 * 68];    // 17.4 KB [b][v-pair]
    __shared__ unsigned Ct[128 * 68];   // 34.8 KB [d][v-pair]
    const int t = threadIdx.x;
    const int vb = blockIdx.x * 128;

#pragma unroll
    for (int i = 0; i < 4; ++i) {
        const int item = i * 256 + t;
        const int q = item & 15;          // b-quad
        const int p = item >> 4;          // v-pair 0..63
        float* w0 = W + (size_t)(vb + 2 * p) * 64 + 4 * q;
        float* w1 = W + (size_t)(vb + 2 * p + 1) * 64 + 4 * q;
        const float4 x = *(const float4*)w0;
        const float4 y = *(const float4*)w1;
        if (rezero) {
            *(float4*)w0 = make_float4(0.f, 0.f, 0.f, 0.f);
            *(float4*)w1 = make_float4(0.f, 0.f, 0.f, 0.f);
        }
        Wt[(4 * q + 0) * 68 + p] = pk2(x.x, y.x);
        Wt[(4 * q + 1) * 68 + p] = pk2(x.y, y.y);
        Wt[(4 * q + 2) * 68 + p] = pk2(x.z, y.z);
        Wt[(4 * q + 3) * 68 + p] = pk2(x.w, y.w);
    }
#pragma unroll
    for (int i = 0; i < 8; ++i) {
        const int item = i * 256 + t;
        const int q = item & 31;          // d-quad
        const int p = item >> 5;          // v-pair 0..63
        const int v0 = vb + 2 * p;
        const float4 x = (v0 < VV)
            ? *(const float4*)(C2 + (size_t)v0 * DD + 4 * q)
            : make_float4(0.f, 0.f, 0.f, 0.f);
        const float4 y = (v0 + 1 < VV)
            ? *(const float4*)(C2 + (size_t)(v0 + 1) * DD + 4 * q)
            : make_float4(0.f, 0.f, 0.f, 0.f);
        Ct[(4 * q + 0) * 68 + p] = pk2(x.x, y.x);
        Ct[(4 * q + 1) * 68 + p] = pk2(x.y, y.y);
        Ct[(4 * q + 2) * 68 + p] = pk2(x.z, y.z);
        Ct[(4 * q + 3) * 68 + p] = pk2(x.w, y.w);
    }
    __syncthreads();

    const int l = t & 63;
    const int w = t >> 6;       // wave: d-cols 32w..32w+31
    const int quad = l >> 4;
    const int n16 = l & 15;

    f4v a00 = {0.f, 0.f, 0.f, 0.f}, a01 = a00;
    f4v a10 = a00, a11 = a00, a20 = a00, a21 = a00, a30 = a00, a31 = a00;

#pragma unroll
    for (int ch = 0; ch < 4; ++ch) {
        const int ku = ch * 16 + quad * 4;   // uint col: k = 2*ku..2*ku+7
        const s8v wa0 = *(const s8v*)&Wt[(0  + n16) * 68 + ku];
        const s8v wa1 = *(const s8v*)&Wt[(16 + n16) * 68 + ku];
        const s8v wa2 = *(const s8v*)&Wt[(32 + n16) * 68 + ku];
        const s8v wa3 = *(const s8v*)&Wt[(48 + n16) * 68 + ku];
        const s8v cb0 = *(const s8v*)&Ct[(w * 32 + n16) * 68 + ku];
        const s8v cb1 = *(const s8v*)&Ct[(w * 32 + 16 + n16) * 68 + ku];
        a00 = __builtin_amdgcn_mfma_f32_16x16x32_bf16(wa0, cb0, a00, 0, 0, 0);
        a01 = __builtin_amdgcn_mfma_f32_16x16x32_bf16(wa0, cb1, a01, 0, 0, 0);
        a10 = __builtin_amdgcn_mfma_f32_16x16x32_bf16(wa1, cb0, a10, 0, 0, 0);
        a11 = __builtin_amdgcn_mfma_f32_16x16x32_bf16(wa1, cb1, a11, 0, 0, 0);
        a20 = __builtin_amdgcn_mfma_f32_16x16x32_bf16(wa2, cb0, a20, 0, 0, 0);
        a21 = __builtin_amdgcn_mfma_f32_16x16x32_bf16(wa2, cb1, a21, 0, 0, 0);
        a30 = __builtin_amdgcn_mfma_f32_16x16x32_bf16(wa3, cb0, a30, 0, 0, 0);
        a31 = __builtin_amdgcn_mfma_f32_16x16x32_bf16(wa3, cb1, a31, 0, 0, 0);
    }

    // pack (d0, d0+16) pairs as bf16x2: halves partial traffic both ways
    unsigned* __restrict__ up = upk + (size_t)blockIdx.x * (BB * 64);
    const int wi = w * 16 + n16;
#pragma unroll
    for (int r = 0; r < 4; ++r) {
        const int br = quad * 4 + r;
        up[(br +  0) * 64 + wi] = pk2(a00[r], a01[r]);
        up[(br + 16) * 64 + wi] = pk2(a10[r], a11[r]);
        up[(br + 32) * 64 + wi] = pk2(a20[r], a21[r]);
        up[(br + 48) * 64 + wi] = pk2(a30[r], a31[r]);
    }
}

// wave-local Z: wave w of this block owns b = b_base + w (matches jw>>6)
__device__ __forceinline__ float zwave(const float* __restrict__ Zp, int b, int tid) {
    const int lane = tid & 63;
    float z = 0.f;
#pragma unroll
    for (int i = 0; i < 8; ++i)
        z += Zp[(size_t)(lane * 8 + i) * 64 + b];
#pragma unroll
    for (int off = 32; off; off >>= 1) z += __shfl_xor(z, off, 64);
    return z;   // uniform across the wave
}

// ---- reduce hop 0 (prob exact): u += unpacked partial sums ----
// 128 blocks (16 jc x 8 kc); word jw -> b=jw>>6, wi=jw&63, d0/(d0+16).
__global__ __launch_bounds__(256) void k_reduce_a(const unsigned* __restrict__ upk,
                                                  float* __restrict__ u) {
    const int jc = blockIdx.x & 15;
    const int kc = blockIdx.x >> 4;   // 8 k-chunks of 49
    const int jw = jc * 256 + threadIdx.x;     // 0..4095
    const unsigned* __restrict__ p = upk + (size_t)kc * 49 * (BB * 64) + jw;
    float lo = 0.f, hi = 0.f;
#pragma unroll 7
    for (int k = 0; k < 49; ++k) {
        const unsigned w = p[(size_t)k * (BB * 64)];
        lo += bf2f((unsigned short)w);
        hi += bf2f((unsigned short)(w >> 16));
    }
    const int b = jw >> 6, wi = jw & 63;
    const int d0 = (wi >> 4) * 32 + (wi & 15);
    atomicAdd(u + b * DD + d0, lo);
    atomicAdd(u + b * DD + d0 + 16, hi);
}

// ---- reduce hops 1 (unnormalized W): u += sums * (1/Z[b]) ----
__global__ __launch_bounds__(256) void k_reduce_az(const unsigned* __restrict__ upk,
                                                   const float* __restrict__ Zp,
                                                   float* __restrict__ u) {
    const int jc = blockIdx.x & 15;
    const int kc = blockIdx.x >> 4;
    const int tid = threadIdx.x;
    const int jw = jc * 256 + tid;
    const int b = jw >> 6;            // = jc*4 + (tid>>6): wave-aligned
    const float rz = 1.f / zwave(Zp, b, tid);
    const unsigned* __restrict__ p = upk + (size_t)kc * 49 * (BB * 64) + jw;
    float lo = 0.f, hi = 0.f;
#pragma unroll 7
    for (int k = 0; k < 49; ++k) {
        const unsigned w = p[(size_t)k * (BB * 64)];
        lo += bf2f((unsigned short)w);
        hi += bf2f((unsigned short)(w >> 16));
    }
    const int wi = jw & 63;
    const int d0 = (wi >> 4) * 32 + (wi & 15);
    atomicAdd(u + b * DD + d0, lo * rz);
    atomicAdd(u + b * DD + d0 + 16, hi * rz);
}

// ---- final reduce hop 2: out = u + sums * (1/Z[b]); 16 blocks owner-computes ----
__global__ __launch_bounds__(256) void k_reduce_finz(const unsigned* __restrict__ upk,
                                                     const float* __restrict__ Zp,
                                                     const float* __restrict__ u,
                                                     float* __restrict__ out) {
    const int tid = threadIdx.x;
    const int jw = blockIdx.x * 256 + tid;   // 0..4095
    const int b = jw >> 6;                   // wave-aligned
    const float rz = 1.f / zwave(Zp, b, tid);
    const unsigned* __restrict__ p = upk + jw;
    float lo = 0.f, hi = 0.f;
#pragma unroll 8
    for (int k = 0; k < NPART; ++k) {
        const unsigned w = p[(size_t)k * (BB * 64)];
        lo += bf2f((unsigned short)w);
        hi += bf2f((unsigned short)(w >> 16));
    }
    const int wi = jw & 63;
    const int d0 = (wi >> 4) * 32 + (wi & 15);
    out[b * DD + d0]      = u[b * DD + d0]      + lo * rz;
    out[b * DD + d0 + 16] = u[b * DD + d0 + 16] + hi * rz;
}

extern "C" void kernel_launch(void* const* d_in, const int* in_sizes, int n_in,
                              void* d_out, int out_size, void* d_ws, size_t ws_size,
                              hipStream_t stream) {
    const int* st = (const int*)d_in[0];
    const float* C = (const float*)d_in[1];

    float* u  = (float*)d_ws;                 // 8192 f, [b][d]
    float* W  = u + BB * DD;                  // VPAD*64 f (scatter target)
    float* P  = W + (size_t)VPAD * BB;        // VPAD*64 f (GEMM1 output)
    unsigned* upk = (unsigned*)(P + (size_t)VPAD * BB);  // NPART*4096 u32
    float* Zp = (float*)(upk + (size_t)NPART * BB * 64); // 512*64 f

    // zero u + W once; W self-cleans each hop via gemm_o writeback
    k_init<<<(BB * DD + VPAD * BB) / 1024, 256, 0, stream>>>((float4*)u);

    // ---- hop 0: prob exactly uniform 1/2048 (u=0) — no GEMM1/attn ----
    k_scatter0<<<(MM * BB) / 256, 256, 0, stream>>>(st, W);
    k_gemm_o<<<VPAD / 128, 256, 0, stream>>>(C + (size_t)1 * VV * DD, W, upk, 1);
    k_reduce_a<<<128, 256, 0, stream>>>(upk, u);

    // ---- hop 1 ----
    k_gemm_p<<<VPAD / 128, 256, 0, stream>>>(C + (size_t)1 * VV * DD, u, P);
    k_attn2<<<NATT, 256, 0, stream>>>(st, P, W, Zp);
    k_gemm_o<<<VPAD / 128, 256, 0, stream>>>(C + (size_t)2 * VV * DD, W, upk, 1);
    k_reduce_az<<<128, 256, 0, stream>>>(upk, Zp, u);

    // ---- hop 2 ----
    k_gemm_p<<<VPAD / 128, 256, 0, stream>>>(C + (size_t)2 * VV * DD, u, P);
    k_attn2<<<NATT, 256, 0, stream>>>(st, P, W, Zp);
    k_gemm_o<<<VPAD / 128, 256, 0, stream>>>(C + (size_t)3 * VV * DD, W, upk, 0);
    k_reduce_finz<<<16, 256, 0, stream>>>(upk, Zp, u, (float*)d_out);
}